// Round 8
// baseline (174.630 us; speedup 1.0000x reference)
//
#include <hip/hip_runtime.h>

#define N_NODES_C 8192
#define N_EDGES_C 262144
#define MAX_PATH_C 5
#define EDGE_DIM_C 32

typedef unsigned int uint4_v __attribute__((ext_vector_type(4)));

// ---- d_ws layout (32-bit words) ----
#define WS_CNT    0
#define WS_OFFS   8192
#define WS_CURSOR 24576
#define WS_PATHID 32768
#define WS_ENC    (32768 + 1048576)          // 1081344
#define WS_D      (WS_ENC + 1048576)          // 2129920; D[e*8+l], 8MB

// Precompute D[e][l] = edge_attr[e] . edge_weights[l]; also zero cnt.
__global__ void __launch_bounds__(256) k_edge_dots(
    const float* __restrict__ edge_attr,
    const float* __restrict__ edge_weights,
    float* __restrict__ D,
    unsigned int* __restrict__ cnt)
{
    __shared__ __align__(16) float w[MAX_PATH_C * EDGE_DIM_C];
    for (int i = threadIdx.x; i < MAX_PATH_C * EDGE_DIM_C; i += blockDim.x)
        w[i] = edge_weights[i];
    __syncthreads();

    int e = blockIdx.x * blockDim.x + threadIdx.x;
    if (e < N_NODES_C) cnt[e] = 0u;
    if (e >= N_EDGES_C) return;

    const float4* __restrict__ row = (const float4*)(edge_attr + (size_t)e * EDGE_DIM_C);
    float4 a[EDGE_DIM_C / 4];
    #pragma unroll
    for (int j = 0; j < EDGE_DIM_C / 4; ++j) a[j] = row[j];

    float d[MAX_PATH_C];
    #pragma unroll
    for (int l = 0; l < MAX_PATH_C; ++l) {
        const float4* wr = (const float4*)(w + l * EDGE_DIM_C);
        float acc = 0.0f;
        #pragma unroll
        for (int j = 0; j < EDGE_DIM_C / 4; ++j) {
            float4 b = wr[j];
            acc += a[j].x * b.x + a[j].y * b.y + a[j].z * b.z + a[j].w * b.w;
        }
        d[l] = acc;
    }
    float4* Dp = (float4*)(D + (size_t)e * 8);
    Dp[0] = make_float4(d[0], d[1], d[2], d[3]);
    Dp[1] = make_float4(d[4], 0.0f, 0.0f, 0.0f);
}

// Per-path encoding from the small D table + histogram by src row.
__global__ void __launch_bounds__(256) k_path_enc(
    const float* __restrict__ D,
    const int* __restrict__ paths,
    const int* __restrict__ path_lens,
    const int* __restrict__ src,
    unsigned int* __restrict__ cnt,
    float* __restrict__ enc_out, int P)
{
    int p = blockIdx.x * blockDim.x + threadIdx.x;
    if (p >= P) return;

    atomicAdd(&cnt[src[p]], 1u);

    int len = path_lens[p];
    float s = 0.0f;
    #pragma unroll
    for (int l = 0; l < MAX_PATH_C; ++l) {
        if (l < len) {
            int e = paths[p * MAX_PATH_C + l];
            s += D[(size_t)e * 8 + l];
        }
    }
    float enc = (len > 0) ? s / (float)len : 0.0f;
    if (isnan(enc)) enc = 0.0f;  // nan_to_num
    enc_out[p] = enc;
}

// Exclusive prefix sum over 8192 counters; writes offs[0..8192] and cursor.
__global__ void __launch_bounds__(1024) k_scan(
    const unsigned int* __restrict__ cnt,
    unsigned int* __restrict__ offs,
    unsigned int* __restrict__ cursor)
{
    __shared__ unsigned int part[1024];
    int t = threadIdx.x;
    unsigned int local[8];
    unsigned int mysum = 0;
    #pragma unroll
    for (int j = 0; j < 8; ++j) { local[j] = cnt[t * 8 + j]; mysum += local[j]; }
    part[t] = mysum;
    __syncthreads();
    for (int off = 1; off < 1024; off <<= 1) {
        unsigned int v = 0;
        if (t >= off) v = part[t - off];
        __syncthreads();
        if (t >= off) part[t] += v;
        __syncthreads();
    }
    unsigned int run = part[t] - mysum;  // exclusive base
    #pragma unroll
    for (int j = 0; j < 8; ++j) {
        offs[t * 8 + j] = run;
        cursor[t * 8 + j] = run;
        run += local[j];
    }
    if (t == 1023) offs[N_NODES_C] = run;
}

// Bucket path ids by src row.
__global__ void __launch_bounds__(256) k_scatter(
    const int* __restrict__ src,
    unsigned int* __restrict__ cursor,
    unsigned int* __restrict__ pathid, int P)
{
    int p = blockIdx.x * blockDim.x + threadIdx.x;
    if (p >= P) return;
    unsigned int pos = atomicAdd(&cursor[src[p]], 1u);
    pathid[pos] = (unsigned int)p;
}

// One block per output row: build row in LDS, stream out with NT stores.
// d_out is written exactly once per line, by a fixed owner block, never read.
__global__ void __launch_bounds__(256) k_sweep(
    const unsigned int* __restrict__ offs,
    const unsigned int* __restrict__ pathid,
    const float* __restrict__ enc,
    const int* __restrict__ dst,
    float* __restrict__ out)
{
    __shared__ __align__(16) unsigned int row[N_NODES_C];
    const int r = blockIdx.x;
    const int t = threadIdx.x;

    uint4_v* row4 = (uint4_v*)row;
    uint4_v z = (uint4_v)(0u);
    #pragma unroll
    for (int j = 0; j < 8; ++j) row4[j * 256 + t] = z;
    __syncthreads();

    const unsigned int beg = offs[r], end = offs[r + 1];
    for (unsigned int i = beg + t; i < end; i += 256) {
        unsigned int p = pathid[i];
        atomicMax(&row[dst[p]], p + 1u);  // last-write-wins tag
    }
    __syncthreads();
    for (unsigned int i = beg + t; i < end; i += 256) {
        unsigned int p = pathid[i];
        int d = dst[p];
        if (row[d] == p + 1u) row[d] = __float_as_uint(enc[p]);
    }
    __syncthreads();

    uint4_v* out4 = (uint4_v*)(out + (size_t)r * N_NODES_C);
    #pragma unroll
    for (int j = 0; j < 8; ++j)
        __builtin_nontemporal_store(row4[j * 256 + t], &out4[j * 256 + t]);
}

extern "C" void kernel_launch(void* const* d_in, const int* in_sizes, int n_in,
                              void* d_out, int out_size, void* d_ws, size_t ws_size,
                              hipStream_t stream)
{
    // inputs: 0:x 1:edge_attr 2:edge_weights 3:paths 4:path_lens 5:src 6:dst
    const float* edge_attr    = (const float*)d_in[1];
    const float* edge_weights = (const float*)d_in[2];
    const int*   paths        = (const int*)d_in[3];
    const int*   path_lens    = (const int*)d_in[4];
    const int*   src          = (const int*)d_in[5];
    const int*   dst          = (const int*)d_in[6];
    float* out = (float*)d_out;
    const int P = in_sizes[4];

    unsigned int* ws_u = (unsigned int*)d_ws;
    unsigned int* cnt    = ws_u + WS_CNT;
    unsigned int* offs   = ws_u + WS_OFFS;
    unsigned int* cursor = ws_u + WS_CURSOR;
    unsigned int* pathid = ws_u + WS_PATHID;
    float*        enc    = (float*)(ws_u + WS_ENC);
    float*        D      = (float*)(ws_u + WS_D);

    const int threads = 256;
    const int pblocks = (P + threads - 1) / threads;

    k_edge_dots<<<N_EDGES_C / threads, threads, 0, stream>>>(
        edge_attr, edge_weights, D, cnt);
    k_path_enc<<<pblocks, threads, 0, stream>>>(
        D, paths, path_lens, src, cnt, enc, P);
    k_scan<<<1, 1024, 0, stream>>>(cnt, offs, cursor);
    k_scatter<<<pblocks, threads, 0, stream>>>(src, cursor, pathid, P);
    k_sweep<<<N_NODES_C, threads, 0, stream>>>(offs, pathid, enc, dst, out);
}